// Round 6
// baseline (78.831 us; speedup 1.0000x reference)
//
#include <hip/hip_runtime.h>
#include <hip/hip_bf16.h>
#include <cstdint>

// Problem dims (fixed by reference)
#define G_ 256
#define P_ 1024
#define D_ 128
#define K_ 16
#define H_ 32
#define N_ (G_ * P_)

// d_out layout (floats), in reference return order
constexpr size_t OFF_COARSE = 0;                               // [G*K, D] = 524288
constexpr size_t OFF_ASSIGN = (size_t)G_ * K_ * D_;            // 524288
constexpr size_t OFF_SEND   = OFF_ASSIGN + (size_t)N_ * K_;    // 4718592
constexpr size_t OFF_RECV   = OFF_SEND + (size_t)G_ * K_ * K_; // 4784128
constexpr size_t OFF_EDGE   = OFF_RECV + (size_t)G_ * K_ * K_; // 4849664

typedef __attribute__((ext_vector_type(8))) short bf16x8;   // 8 bf16 (4 VGPR)
typedef __attribute__((ext_vector_type(4))) float f32x4;    // MFMA C/D

// split x ~= hi + lo (bf16 each, truncation + residual): 3-MFMA ~f32 GEMM
__device__ __forceinline__ void splitf(float x, short& h, short& l) {
    const unsigned u = __float_as_uint(x);
    h = (short)(u >> 16);
    const float hf = __uint_as_float(u & 0xffff0000u);
    const float r = x - hf;
    l = (short)(__float_as_uint(r) >> 16);
}

// ---------------------------------------------------------------------------
// Kernel 1 (v4): MFMA MLP + softmax, reg-staged XOR-swizzled LDS x-tiles.
// R5 was latency-bound: strided 16B fragment loads (2x transactions) at
// 2 waves/SIMD. Now: per wave, per 16-node sub-tile, 8 coalesced dwordx4
// loads -> swizzled wave-private LDS ([kb][16 rows][32 f], byte^=(row&7)<<4)
// -> ds_read_b128 fragments (~2-way banks = free). Next sub-tile's global
// loads are issued before compute (T14). Layer 2 fused per sub-tile; h goes
// through a 2KB wave-private LDS transpose packed as (bf16_hi<<16)|bf16_lo.
// No __syncthreads anywhere: all LDS is wave-private (same-wave DS order).
// Fragment maps (16x16x32 bf16): A row=lane&15, k=(lane>>4)*8+e; B col=lane&15;
// C/D col=lane&15, row=(lane>>4)*4+reg [m89/m91; validated by R5 absmax].
// ---------------------------------------------------------------------------
__global__ __launch_bounds__(256, 3) void mlp_assign_mfma(
    const float* __restrict__ x, const float* __restrict__ W1,
    const float* __restrict__ b1, const float* __restrict__ W2,
    const float* __restrict__ b2, float* __restrict__ assign_out)
{
    __shared__ float    xstage[4][2048];   // per-wave 8KB: [kb][16][32] XOR-swz
    __shared__ unsigned hstage[4][512];    // per-wave 2KB: [16][32] u32 hi|lo, XOR-swz

    const int tid  = threadIdx.x;
    const int lane = tid & 63;
    const int wave = tid >> 6;
    const int q = lane >> 4;   // 0..3
    const int c = lane & 15;   // 0..15

    // ---- persistent W fragments (one-time, L1/L2-served) ----
    bf16x8 w1h[4][2], w1l[4][2];
#pragma unroll
    for (int kb = 0; kb < 4; ++kb)
#pragma unroll
        for (int nt = 0; nt < 2; ++nt)
#pragma unroll
            for (int e = 0; e < 8; ++e) {
                short hb, lb;
                splitf(W1[(kb * 32 + q * 8 + e) * H_ + nt * 16 + c], hb, lb);
                w1h[kb][nt][e] = hb; w1l[kb][nt][e] = lb;
            }
    bf16x8 w2h, w2l;
#pragma unroll
    for (int e = 0; e < 8; ++e) {
        short hb, lb;
        splitf(W2[(q * 8 + e) * K_ + c], hb, lb);
        w2h[e] = hb; w2l[e] = lb;
    }
    const float b1v0 = b1[c];
    const float b1v1 = b1[16 + c];
    const float b2v  = b2[c];

    float* xw = xstage[wave];
    unsigned* hw = hstage[wave];
    const size_t nodebase = (size_t)blockIdx.x * 256 + (size_t)wave * 64;

    // preload sub-tile 0 (16 rows x 128 f = 8KB): 8 coalesced dwordx4/lane
    float4 ld[8];
    {
        const float4* src = (const float4*)(x + nodebase * D_);
#pragma unroll
        for (int i = 0; i < 8; ++i) ld[i] = src[i * 64 + lane];
    }

#pragma unroll
    for (int mt = 0; mt < 4; ++mt) {
        // ---- stage sub-tile mt into swizzled LDS ----
#pragma unroll
        for (int i = 0; i < 8; ++i) {
            const int cid  = i * 64 + lane;       // float4 id in 8KB tile
            const int row  = cid >> 5;            // 32 float4 per 512B row
            const int colf = (cid & 31) * 4;      // float col in row
            const int kb   = colf >> 5;
            const int win  = colf & 31;
            const int addr = (kb * 2048 + row * 128 + win * 4) ^ ((row & 7) << 4);
            *(float4*)((char*)xw + addr) = ld[i];
        }

        // ---- issue sub-tile mt+1 loads (fly under MFMA below) ----
        if (mt < 3) {
            const float4* src = (const float4*)(x + (nodebase + (size_t)(mt + 1) * 16) * D_);
#pragma unroll
            for (int i = 0; i < 8; ++i) ld[i] = src[i * 64 + lane];
        }

        // ---- layer 1: acc[16 nodes x 32 j] over 4 k-blocks ----
        f32x4 acc0 = {b1v0, b1v0, b1v0, b1v0};
        f32x4 acc1 = {b1v1, b1v1, b1v1, b1v1};
#pragma unroll
        for (int kb = 0; kb < 4; ++kb) {
            const int rb = kb * 2048 + c * 128 + q * 32;
            const int sw = (c & 7) << 4;
            const float4 v0 = *(const float4*)((char*)xw + (rb ^ sw));
            const float4 v1 = *(const float4*)((char*)xw + ((rb + 16) ^ sw));
            const float vv[8] = {v0.x, v0.y, v0.z, v0.w, v1.x, v1.y, v1.z, v1.w};
            bf16x8 ah, al;
#pragma unroll
            for (int e = 0; e < 8; ++e) {
                short hb, lb; splitf(vv[e], hb, lb);
                ah[e] = hb; al[e] = lb;
            }
            acc0 = __builtin_amdgcn_mfma_f32_16x16x32_bf16(ah, w1h[kb][0], acc0, 0, 0, 0);
            acc0 = __builtin_amdgcn_mfma_f32_16x16x32_bf16(ah, w1l[kb][0], acc0, 0, 0, 0);
            acc0 = __builtin_amdgcn_mfma_f32_16x16x32_bf16(al, w1h[kb][0], acc0, 0, 0, 0);
            acc1 = __builtin_amdgcn_mfma_f32_16x16x32_bf16(ah, w1h[kb][1], acc1, 0, 0, 0);
            acc1 = __builtin_amdgcn_mfma_f32_16x16x32_bf16(ah, w1l[kb][1], acc1, 0, 0, 0);
            acc1 = __builtin_amdgcn_mfma_f32_16x16x32_bf16(al, w1h[kb][1], acc1, 0, 0, 0);
        }

        // ---- relu + split-pack h into wave-private LDS (transpose) ----
#pragma unroll
        for (int r = 0; r < 4; ++r) {
            const int row = q * 4 + r;
            const int xsw = (row & 7) << 2;   // u32-index XOR (byte<<4)
            short hb, lb;
            const float t0 = fmaxf(acc0[r], 0.f);
            splitf(t0, hb, lb);
            hw[(row * 32 + c) ^ xsw] =
                ((unsigned)(unsigned short)hb << 16) | (unsigned short)lb;
            const float t1 = fmaxf(acc1[r], 0.f);
            splitf(t1, hb, lb);
            hw[(row * 32 + 16 + c) ^ xsw] =
                ((unsigned)(unsigned short)hb << 16) | (unsigned short)lb;
        }

        // ---- layer 2: logits[16 x 16] = relu(h) @ W2 + b2 ----
        const int hsw = (c & 7) << 2;
        const uint4 u0 = *(const uint4*)&hw[(c * 32 + q * 8) ^ hsw];
        const uint4 u1 = *(const uint4*)&hw[(c * 32 + q * 8 + 4) ^ hsw];
        const unsigned uu[8] = {u0.x, u0.y, u0.z, u0.w, u1.x, u1.y, u1.z, u1.w};
        bf16x8 ha, la;
#pragma unroll
        for (int e = 0; e < 8; ++e) {
            ha[e] = (short)(uu[e] >> 16);
            la[e] = (short)(uu[e] & 0xffffu);
        }
        f32x4 lacc = {b2v, b2v, b2v, b2v};
        lacc = __builtin_amdgcn_mfma_f32_16x16x32_bf16(ha, w2h, lacc, 0, 0, 0);
        lacc = __builtin_amdgcn_mfma_f32_16x16x32_bf16(ha, w2l, lacc, 0, 0, 0);
        lacc = __builtin_amdgcn_mfma_f32_16x16x32_bf16(la, w2h, lacc, 0, 0, 0);

        // ---- softmax over K=16 (16-lane shfl groups) + store ----
#pragma unroll
        for (int r = 0; r < 4; ++r) {
            const float v = lacc[r];
            float mx = v;
#pragma unroll
            for (int s = 1; s < 16; s <<= 1) mx = fmaxf(mx, __shfl_xor(mx, s, 16));
            const float e = __expf(v - mx);
            float sum = e;
#pragma unroll
            for (int s = 1; s < 16; s <<= 1) sum += __shfl_xor(sum, s, 16);
            assign_out[(nodebase + (size_t)mt * 16 + q * 4 + r) * K_ + c] = e / sum;
        }
    }
}

// ---------------------------------------------------------------------------
// Kernel 2 (v4): coarse segment-sum + fused edge writer.
// One block per graph, 1024 threads, 32-node LDS chunks, double-buffered
// reg->LDS staging; thread = (dq, s) owns all 16 k; acc all-static-index.
// ---------------------------------------------------------------------------
#define FMA4(dst, v, sc)                                                      \
    dst.x = fmaf(v.x, sc, dst.x); dst.y = fmaf(v.y, sc, dst.y);               \
    dst.z = fmaf(v.z, sc, dst.z); dst.w = fmaf(v.w, sc, dst.w)

__global__ __launch_bounds__(1024, 4) void coarse_kernel(
    const float* __restrict__ x, const float* __restrict__ assign,
    const int* __restrict__ n_node, float* __restrict__ out)
{
    __shared__ float xs[2][32 * 128];
    __shared__ float as_[2][32 * 16];
    __shared__ int pref[G_];

    const int tid = threadIdx.x;
    const int g = blockIdx.x;

    // fused fully-connected coarse-edge outputs (256 edges per graph)
    if (tid < 256) {
        const int e = g * 256 + tid;
        out[OFF_SEND + e] = (float)(g * K_ + (tid >> 4));
        out[OFF_RECV + e] = (float)(g * K_ + (tid & 15));
        out[OFF_EDGE + e] = 1.0f;
    }

    if (tid < G_) pref[tid] = n_node[tid];
    __syncthreads();
    for (int st = 1; st < G_; st <<= 1) {
        int v = 0;
        if (tid < G_ && tid >= st) v = pref[tid - st];
        __syncthreads();
        if (tid < G_ && tid >= st) pref[tid] += v;
        __syncthreads();
    }
    const int start = (g == 0) ? 0 : min(pref[g - 1], N_);
    const int end   = (g == G_ - 1) ? N_ : min(pref[g], N_);

    const int dq = tid & 31;
    const int s  = tid >> 5;

    float4 acc[K_];
#pragma unroll
    for (int k = 0; k < K_; ++k) acc[k] = make_float4(0.f, 0.f, 0.f, 0.f);

    const int total = end - start;
    const int nfull = total >> 5;
    const int tail  = total & 31;

    float4 rx = make_float4(0.f, 0.f, 0.f, 0.f);
    float4 ra = make_float4(0.f, 0.f, 0.f, 0.f);
    if (nfull > 0) {
        rx = *(const float4*)(x + (size_t)start * D_ + tid * 4);
        if (tid < 128)
            ra = *(const float4*)(assign + (size_t)start * K_ + tid * 4);
    }

    int b = 0;
    for (int cc = 0; cc < nfull; ++cc) {
        *(float4*)(&xs[b][tid * 4]) = rx;
        if (tid < 128) *(float4*)(&as_[b][tid * 4]) = ra;
        __syncthreads();

        if (cc + 1 < nfull) {
            const size_t nb = (size_t)start + (size_t)(cc + 1) * 32;
            rx = *(const float4*)(x + nb * D_ + tid * 4);
            if (tid < 128)
                ra = *(const float4*)(assign + nb * K_ + tid * 4);
        }

        const float4 xv = *(const float4*)(&xs[b][s * D_ + dq * 4]);
        const float4* av = (const float4*)(&as_[b][s * K_]);
#pragma unroll
        for (int qq = 0; qq < 4; ++qq) {
            const float4 a = av[qq];
            FMA4(acc[4 * qq + 0], xv, a.x);
            FMA4(acc[4 * qq + 1], xv, a.y);
            FMA4(acc[4 * qq + 2], xv, a.z);
            FMA4(acc[4 * qq + 3], xv, a.w);
        }
        b ^= 1;
    }

    if (tail > 0 && s < tail) {
        const size_t n = (size_t)start + (size_t)nfull * 32 + s;
        const float4 xv = *(const float4*)(x + n * D_ + dq * 4);
        const float4* av = (const float4*)(assign + n * K_);
#pragma unroll
        for (int qq = 0; qq < 4; ++qq) {
            const float4 a = av[qq];
            FMA4(acc[4 * qq + 0], xv, a.x);
            FMA4(acc[4 * qq + 1], xv, a.y);
            FMA4(acc[4 * qq + 2], xv, a.z);
            FMA4(acc[4 * qq + 3], xv, a.w);
        }
    }

    __syncthreads();
    float* red = &xs[0][0];
#pragma unroll
    for (int k = 0; k < K_; ++k) {
        *(float4*)(&red[s * D_ + dq * 4]) = acc[k];
        __syncthreads();
        if (tid < D_) {
            float sum = 0.f;
#pragma unroll
            for (int ss = 0; ss < 32; ++ss) sum += red[ss * D_ + tid];
            out[OFF_COARSE + ((size_t)g * K_ + k) * D_ + tid] = sum;
        }
        __syncthreads();
    }
}

extern "C" void kernel_launch(void* const* d_in, const int* in_sizes, int n_in,
                              void* d_out, int out_size, void* d_ws, size_t ws_size,
                              hipStream_t stream)
{
    const float* x      = (const float*)d_in[0];
    const float* W1     = (const float*)d_in[1];
    const float* b1     = (const float*)d_in[2];
    const float* W2     = (const float*)d_in[3];
    const float* b2     = (const float*)d_in[4];
    const int*   n_node = (const int*)d_in[5];
    float* out = (float*)d_out;

    mlp_assign_mfma<<<N_ / 256, 256, 0, stream>>>(x, W1, b1, W2, b2, out + OFF_ASSIGN);
    coarse_kernel<<<G_, 1024, 0, stream>>>(x, out + OFF_ASSIGN, n_node, out);
}

// Round 8
// 65.616 us; speedup vs baseline: 1.2014x; 1.2014x over previous
//
#include <hip/hip_runtime.h>
#include <hip/hip_bf16.h>
#include <cstdint>

// Problem dims (fixed by reference)
#define G_ 256
#define P_ 1024
#define D_ 128
#define K_ 16
#define H_ 32
#define N_ (G_ * P_)

// d_out layout (floats), in reference return order
constexpr size_t OFF_COARSE = 0;                               // [G*K, D] = 524288
constexpr size_t OFF_ASSIGN = (size_t)G_ * K_ * D_;            // 524288
constexpr size_t OFF_SEND   = OFF_ASSIGN + (size_t)N_ * K_;    // 4718592
constexpr size_t OFF_RECV   = OFF_SEND + (size_t)G_ * K_ * K_; // 4784128
constexpr size_t OFF_EDGE   = OFF_RECV + (size_t)G_ * K_ * K_; // 4849664

typedef __attribute__((ext_vector_type(8))) short bf16x8;   // 8 bf16 (4 VGPR)
typedef __attribute__((ext_vector_type(4))) float f32x4;    // MFMA C/D

// split x ~= hi + lo (bf16 each, truncation + residual): 3-MFMA ~f32 GEMM
__device__ __forceinline__ void splitf(float x, short& h, short& l) {
    const unsigned u = __float_as_uint(x);
    h = (short)(u >> 16);
    const float hf = __uint_as_float(u & 0xffff0000u);
    const float r = x - hf;
    l = (short)(__float_as_uint(r) >> 16);
}

// ---------------------------------------------------------------------------
// Kernel 1 (v5b): MFMA MLP + softmax. Same as R7 with the W1-staging kb bit
// fix: kb lives at bits 10-11 of i (e:3b, cc:4b, qq:2b, nt:1b, kb:2b) — R7
// used (i>>11)&3, leaving kb=2,3 fragments uninitialized -> NaN.
// Design: W1/W2 (split hi/lo bf16) in block LDS pre-transposed to fragment
// order; x loaded direct global->fragment (R5-validated); reg double-buffer
// across 4 x 16-node tiles; h via wave-private packed-u32 LDS transpose;
// one __syncthreads total. Target: ~110 VGPR -> 4 waves/SIMD.
// Fragment maps (16x16x32 bf16, HW-validated R5/R6): A row=lane&15,
// k=(lane>>4)*8+e; B col=lane&15; C/D col=lane&15, row=(lane>>4)*4+reg.
// ---------------------------------------------------------------------------
__global__ __launch_bounds__(256, 4) void mlp_assign_mfma(
    const float* __restrict__ x, const float* __restrict__ W1,
    const float* __restrict__ b1, const float* __restrict__ W2,
    const float* __restrict__ b2, float* __restrict__ assign_out)
{
    // W1 fragment store: frag f = kb*2+nt (kb k-block 0..3, nt 16-col tile of H)
    // pos = ((f*4 + q)*16 + c)*8 + e  <->  W1[kb*32+q*8+e][nt*16+c]
    __shared__ short w1hi[4096], w1lo[4096];   // 8 KB + 8 KB
    __shared__ short w2hi[512],  w2lo[512];    // 1 KB + 1 KB
    __shared__ unsigned hstage[4][512];        // per-wave 2 KB packed h (hi|lo)

    const int tid  = threadIdx.x;
    const int lane = tid & 63;
    const int wave = tid >> 6;
    const int q = lane >> 4;   // 0..3
    const int c = lane & 15;   // 0..15

    // ---- stage W into LDS in fragment order (one time, one barrier) ----
    for (int i = tid; i < 4096; i += 256) {
        const int e  = i & 7;
        const int cc = (i >> 3) & 15;
        const int qq = (i >> 7) & 3;
        const int nt = (i >> 9) & 1;
        const int kb = (i >> 10) & 3;   // FIX: was (i >> 11) & 3
        short hb, lb;
        splitf(W1[(kb * 32 + qq * 8 + e) * H_ + nt * 16 + cc], hb, lb);
        const int pos = (((kb * 2 + nt) * 4 + qq) * 16 + cc) * 8 + e;
        w1hi[pos] = hb; w1lo[pos] = lb;
    }
    for (int i = tid; i < 512; i += 256) {
        const int e  = i & 7;
        const int cc = (i >> 3) & 15;
        const int qq = (i >> 7) & 3;
        short hb, lb;
        splitf(W2[(qq * 8 + e) * K_ + cc], hb, lb);
        const int pos = (qq * 16 + cc) * 8 + e;
        w2hi[pos] = hb; w2lo[pos] = lb;
    }
    __syncthreads();

    const float b1v0 = b1[c];
    const float b1v1 = b1[16 + c];
    const float b2v  = b2[c];

    unsigned* hw = hstage[wave];
    const size_t nodebase = (size_t)blockIdx.x * 256 + (size_t)wave * 64;

    // direct fragment-layout global loads for a 16-node tile (validated R5)
#define LOAD_TILE(dst, mt)                                                    \
    {                                                                         \
        const float* rp = x + (nodebase + (size_t)(mt) * 16 + c) * D_ + q * 8;\
        _Pragma("unroll")                                                     \
        for (int kb = 0; kb < 4; ++kb) {                                      \
            dst[kb * 2 + 0] = *(const float4*)(rp + kb * 32);                 \
            dst[kb * 2 + 1] = *(const float4*)(rp + kb * 32 + 4);             \
        }                                                                     \
    }

#define PROCESS_TILE(cur, nxt, mt, do_pref)                                   \
    {                                                                         \
        f32x4 acc0 = {b1v0, b1v0, b1v0, b1v0};                                \
        f32x4 acc1 = {b1v1, b1v1, b1v1, b1v1};                                \
        if (do_pref) LOAD_TILE(nxt, (mt) + 1);                                \
        _Pragma("unroll")                                                     \
        for (int kb = 0; kb < 4; ++kb) {                                      \
            const float vv[8] = {cur[kb*2].x, cur[kb*2].y, cur[kb*2].z, cur[kb*2].w, \
                                 cur[kb*2+1].x, cur[kb*2+1].y, cur[kb*2+1].z, cur[kb*2+1].w}; \
            bf16x8 ah, al;                                                    \
            _Pragma("unroll")                                                 \
            for (int e = 0; e < 8; ++e) {                                     \
                short hb, lb; splitf(vv[e], hb, lb);                          \
                ah[e] = hb; al[e] = lb;                                       \
            }                                                                 \
            const bf16x8 bh0 = *(const bf16x8*)&w1hi[((kb * 2 + 0) * 4 + q) * 128 + c * 8]; \
            const bf16x8 bl0 = *(const bf16x8*)&w1lo[((kb * 2 + 0) * 4 + q) * 128 + c * 8]; \
            const bf16x8 bh1 = *(const bf16x8*)&w1hi[((kb * 2 + 1) * 4 + q) * 128 + c * 8]; \
            const bf16x8 bl1 = *(const bf16x8*)&w1lo[((kb * 2 + 1) * 4 + q) * 128 + c * 8]; \
            acc0 = __builtin_amdgcn_mfma_f32_16x16x32_bf16(ah, bh0, acc0, 0, 0, 0); \
            acc0 = __builtin_amdgcn_mfma_f32_16x16x32_bf16(ah, bl0, acc0, 0, 0, 0); \
            acc0 = __builtin_amdgcn_mfma_f32_16x16x32_bf16(al, bh0, acc0, 0, 0, 0); \
            acc1 = __builtin_amdgcn_mfma_f32_16x16x32_bf16(ah, bh1, acc1, 0, 0, 0); \
            acc1 = __builtin_amdgcn_mfma_f32_16x16x32_bf16(ah, bl1, acc1, 0, 0, 0); \
            acc1 = __builtin_amdgcn_mfma_f32_16x16x32_bf16(al, bh1, acc1, 0, 0, 0); \
        }                                                                     \
        /* relu + split-pack h into wave-private LDS (transpose) */           \
        _Pragma("unroll")                                                     \
        for (int r = 0; r < 4; ++r) {                                         \
            const int row = q * 4 + r;                                        \
            const int xsw = (row & 7) << 2;                                   \
            short hb, lb;                                                     \
            splitf(fmaxf(acc0[r], 0.f), hb, lb);                              \
            hw[(row * 32 + c) ^ xsw] =                                        \
                ((unsigned)(unsigned short)hb << 16) | (unsigned short)lb;    \
            splitf(fmaxf(acc1[r], 0.f), hb, lb);                              \
            hw[(row * 32 + 16 + c) ^ xsw] =                                   \
                ((unsigned)(unsigned short)hb << 16) | (unsigned short)lb;    \
        }                                                                     \
        /* layer 2: logits[16x16] = relu(h) @ W2 + b2 (k = H = 32, 1 step) */ \
        {                                                                     \
            const int hsw = (c & 7) << 2;                                     \
            const uint4 u0 = *(const uint4*)&hw[(c * 32 + q * 8) ^ hsw];      \
            const uint4 u1 = *(const uint4*)&hw[(c * 32 + q * 8 + 4) ^ hsw];  \
            const unsigned uu[8] = {u0.x, u0.y, u0.z, u0.w, u1.x, u1.y, u1.z, u1.w}; \
            bf16x8 ha, la;                                                    \
            _Pragma("unroll")                                                 \
            for (int e = 0; e < 8; ++e) {                                     \
                ha[e] = (short)(uu[e] >> 16);                                 \
                la[e] = (short)(uu[e] & 0xffffu);                             \
            }                                                                 \
            const bf16x8 wh = *(const bf16x8*)&w2hi[(q * 16 + c) * 8];        \
            const bf16x8 wl = *(const bf16x8*)&w2lo[(q * 16 + c) * 8];        \
            f32x4 lacc = {b2v, b2v, b2v, b2v};                                \
            lacc = __builtin_amdgcn_mfma_f32_16x16x32_bf16(ha, wh, lacc, 0, 0, 0); \
            lacc = __builtin_amdgcn_mfma_f32_16x16x32_bf16(ha, wl, lacc, 0, 0, 0); \
            lacc = __builtin_amdgcn_mfma_f32_16x16x32_bf16(la, wh, lacc, 0, 0, 0); \
            /* softmax over K=16 (lanes of the q-group) + store */            \
            _Pragma("unroll")                                                 \
            for (int r = 0; r < 4; ++r) {                                     \
                const float v = lacc[r];                                      \
                float mx = v;                                                 \
                _Pragma("unroll")                                             \
                for (int s = 1; s < 16; s <<= 1) mx = fmaxf(mx, __shfl_xor(mx, s, 16)); \
                const float ev = __expf(v - mx);                              \
                float sum = ev;                                               \
                _Pragma("unroll")                                             \
                for (int s = 1; s < 16; s <<= 1) sum += __shfl_xor(sum, s, 16); \
                assign_out[(nodebase + (size_t)(mt) * 16 + q * 4 + r) * K_ + c] = ev / sum; \
            }                                                                 \
        }                                                                     \
    }

    float4 ldA[8], ldB[8];
    LOAD_TILE(ldA, 0);
    PROCESS_TILE(ldA, ldB, 0, true);
    PROCESS_TILE(ldB, ldA, 1, true);
    PROCESS_TILE(ldA, ldB, 2, true);
    PROCESS_TILE(ldB, ldA, 3, false);

#undef LOAD_TILE
#undef PROCESS_TILE
}

// ---------------------------------------------------------------------------
// Kernel 2 (v4): coarse segment-sum + fused edge writer (unchanged, ~6 us).
// ---------------------------------------------------------------------------
#define FMA4(dst, v, sc)                                                      \
    dst.x = fmaf(v.x, sc, dst.x); dst.y = fmaf(v.y, sc, dst.y);               \
    dst.z = fmaf(v.z, sc, dst.z); dst.w = fmaf(v.w, sc, dst.w)

__global__ __launch_bounds__(1024, 4) void coarse_kernel(
    const float* __restrict__ x, const float* __restrict__ assign,
    const int* __restrict__ n_node, float* __restrict__ out)
{
    __shared__ float xs[2][32 * 128];
    __shared__ float as_[2][32 * 16];
    __shared__ int pref[G_];

    const int tid = threadIdx.x;
    const int g = blockIdx.x;

    if (tid < 256) {
        const int e = g * 256 + tid;
        out[OFF_SEND + e] = (float)(g * K_ + (tid >> 4));
        out[OFF_RECV + e] = (float)(g * K_ + (tid & 15));
        out[OFF_EDGE + e] = 1.0f;
    }

    if (tid < G_) pref[tid] = n_node[tid];
    __syncthreads();
    for (int st = 1; st < G_; st <<= 1) {
        int v = 0;
        if (tid < G_ && tid >= st) v = pref[tid - st];
        __syncthreads();
        if (tid < G_ && tid >= st) pref[tid] += v;
        __syncthreads();
    }
    const int start = (g == 0) ? 0 : min(pref[g - 1], N_);
    const int end   = (g == G_ - 1) ? N_ : min(pref[g], N_);

    const int dq = tid & 31;
    const int s  = tid >> 5;

    float4 acc[K_];
#pragma unroll
    for (int k = 0; k < K_; ++k) acc[k] = make_float4(0.f, 0.f, 0.f, 0.f);

    const int total = end - start;
    const int nfull = total >> 5;
    const int tail  = total & 31;

    float4 rx = make_float4(0.f, 0.f, 0.f, 0.f);
    float4 ra = make_float4(0.f, 0.f, 0.f, 0.f);
    if (nfull > 0) {
        rx = *(const float4*)(x + (size_t)start * D_ + tid * 4);
        if (tid < 128)
            ra = *(const float4*)(assign + (size_t)start * K_ + tid * 4);
    }

    int b = 0;
    for (int cc = 0; cc < nfull; ++cc) {
        *(float4*)(&xs[b][tid * 4]) = rx;
        if (tid < 128) *(float4*)(&as_[b][tid * 4]) = ra;
        __syncthreads();

        if (cc + 1 < nfull) {
            const size_t nb = (size_t)start + (size_t)(cc + 1) * 32;
            rx = *(const float4*)(x + nb * D_ + tid * 4);
            if (tid < 128)
                ra = *(const float4*)(assign + nb * K_ + tid * 4);
        }

        const float4 xv = *(const float4*)(&xs[b][s * D_ + dq * 4]);
        const float4* av = (const float4*)(&as_[b][s * K_]);
#pragma unroll
        for (int qq = 0; qq < 4; ++qq) {
            const float4 a = av[qq];
            FMA4(acc[4 * qq + 0], xv, a.x);
            FMA4(acc[4 * qq + 1], xv, a.y);
            FMA4(acc[4 * qq + 2], xv, a.z);
            FMA4(acc[4 * qq + 3], xv, a.w);
        }
        b ^= 1;
    }

    if (tail > 0 && s < tail) {
        const size_t n = (size_t)start + (size_t)nfull * 32 + s;
        const float4 xv = *(const float4*)(x + n * D_ + dq * 4);
        const float4* av = (const float4*)(assign + n * K_);
#pragma unroll
        for (int qq = 0; qq < 4; ++qq) {
            const float4 a = av[qq];
            FMA4(acc[4 * qq + 0], xv, a.x);
            FMA4(acc[4 * qq + 1], xv, a.y);
            FMA4(acc[4 * qq + 2], xv, a.z);
            FMA4(acc[4 * qq + 3], xv, a.w);
        }
    }

    __syncthreads();
    float* red = &xs[0][0];
#pragma unroll
    for (int k = 0; k < K_; ++k) {
        *(float4*)(&red[s * D_ + dq * 4]) = acc[k];
        __syncthreads();
        if (tid < D_) {
            float sum = 0.f;
#pragma unroll
            for (int ss = 0; ss < 32; ++ss) sum += red[ss * D_ + tid];
            out[OFF_COARSE + ((size_t)g * K_ + k) * D_ + tid] = sum;
        }
        __syncthreads();
    }
}

extern "C" void kernel_launch(void* const* d_in, const int* in_sizes, int n_in,
                              void* d_out, int out_size, void* d_ws, size_t ws_size,
                              hipStream_t stream)
{
    const float* x      = (const float*)d_in[0];
    const float* W1     = (const float*)d_in[1];
    const float* b1     = (const float*)d_in[2];
    const float* W2     = (const float*)d_in[3];
    const float* b2     = (const float*)d_in[4];
    const int*   n_node = (const int*)d_in[5];
    float* out = (float*)d_out;

    mlp_assign_mfma<<<N_ / 256, 256, 0, stream>>>(x, W1, b1, W2, b2, out + OFF_ASSIGN);
    coarse_kernel<<<G_, 1024, 0, stream>>>(x, out + OFF_ASSIGN, n_node, out);
}

// Round 10
// 64.842 us; speedup vs baseline: 1.2157x; 1.0119x over previous
//
#include <hip/hip_runtime.h>
#include <hip/hip_bf16.h>
#include <cstdint>

// Problem dims (fixed by reference)
#define G_ 256
#define P_ 1024
#define D_ 128
#define K_ 16
#define H_ 32
#define N_ (G_ * P_)

// d_out layout (floats), in reference return order
constexpr size_t OFF_COARSE = 0;                               // [G*K, D] = 524288
constexpr size_t OFF_ASSIGN = (size_t)G_ * K_ * D_;            // 524288
constexpr size_t OFF_SEND   = OFF_ASSIGN + (size_t)N_ * K_;    // 4718592
constexpr size_t OFF_RECV   = OFF_SEND + (size_t)G_ * K_ * K_; // 4784128
constexpr size_t OFF_EDGE   = OFF_RECV + (size_t)G_ * K_ * K_; // 4849664

typedef __attribute__((ext_vector_type(8))) short bf16x8;   // 8 bf16 (4 VGPR)
typedef __attribute__((ext_vector_type(4))) float f32x4;    // MFMA C/D

// round-to-nearest f32 -> bf16 pair packed in u32 (low = a, high = b)
__device__ __forceinline__ unsigned rpack(float a, float b) {
    const unsigned ua = __float_as_uint(a) + 0x8000u;
    const unsigned ub = __float_as_uint(b) + 0x8000u;
    return (ua >> 16) | (ub & 0xffff0000u);
}
__device__ __forceinline__ short rbf16(float a) {
    return (short)((__float_as_uint(a) + 0x8000u) >> 16);
}

union FragU { uint4 u; bf16x8 v; };

// ---------------------------------------------------------------------------
// Kernel 1 (v6b): all-bf16 MFMA MLP + softmax.
// R9 postmortem: two layer-2 bugs — (a) uint4 read offset +4 OUTSIDE the
// swizzle XOR (carry corrupts swizzle bits; R8's validated form has it
// INSIDE: (base+4)^swz), (b) stray ha.u.x=0 in the unrolled repack loop.
// v6b reverts the h path to R8's byte-exact addressing: hstage[4][512],
// write (row*32+c)^xsw and (row*32+16+c)^xsw with xsw=(row&7)<<2; read
// u0 at (c*32+q*8)^hsw, u1 at (c*32+q*8+4)^hsw with hsw=(c&7)<<2. Each
// u32 slot now holds ONE bf16 h value (low 16 bits); ha = low halves.
// Precision plan (R9 theory, now actually tested): single bf16-RN MFMA
// per product (no hi/lo split: 1/3 the MFMA, ~1/2 the VALU), softmax
// without max-subtract (|logit| <~ 5 << 88, f32 exp safe).
// Fragment maps (16x16x32 bf16, HW-validated R5-R8): A row=lane&15,
// k=(lane>>4)*8+e; B col=lane&15; C/D col=lane&15, row=(lane>>4)*4+reg.
// ---------------------------------------------------------------------------
__global__ __launch_bounds__(256, 4) void mlp_assign_mfma(
    const float* __restrict__ x, const float* __restrict__ W1,
    const float* __restrict__ b1, const float* __restrict__ W2,
    const float* __restrict__ b2, float* __restrict__ assign_out)
{
    __shared__ short    w1s[4096];       // 8 KB: frag order ((kb*2+nt)*4+q)*128 + c*8 + e
    __shared__ unsigned hstage[4][512];  // per-wave 2 KB: R8-validated layout

    const int tid  = threadIdx.x;
    const int lane = tid & 63;
    const int wave = tid >> 6;
    const int q = lane >> 4;   // 0..3
    const int c = lane & 15;   // 0..15

    // ---- stage W1 (bf16-RN) into LDS in fragment order ----
    for (int i = tid; i < 4096; i += 256) {
        const int e  = i & 7;
        const int cc = (i >> 3) & 15;
        const int qq = (i >> 7) & 3;
        const int nt = (i >> 9) & 1;
        const int kb = (i >> 10) & 3;
        w1s[(((kb * 2 + nt) * 4 + qq) * 16 + cc) * 8 + e] =
            rbf16(W1[(kb * 32 + qq * 8 + e) * H_ + nt * 16 + cc]);
    }
    __syncthreads();

    // ---- W2 fragment in registers (k=j=q*8+e, col=c) ----
    FragU w2f;
    {
        float wv[8];
#pragma unroll
        for (int e = 0; e < 8; ++e) wv[e] = W2[(q * 8 + e) * K_ + c];
        w2f.u = make_uint4(rpack(wv[0], wv[1]), rpack(wv[2], wv[3]),
                           rpack(wv[4], wv[5]), rpack(wv[6], wv[7]));
    }
    const float b1v0 = b1[c];
    const float b1v1 = b1[16 + c];
    const float b2v  = b2[c];

    unsigned* hw = hstage[wave];
    const size_t nodebase = (size_t)blockIdx.x * 256 + (size_t)wave * 64;

    // direct fragment-layout global loads (R5-validated): row = c, k = q*8+e
    float4 ld[8];
    {
        const float* rp = x + (nodebase + c) * D_ + q * 8;
#pragma unroll
        for (int kb = 0; kb < 4; ++kb) {
            ld[kb * 2 + 0] = *(const float4*)(rp + kb * 32);
            ld[kb * 2 + 1] = *(const float4*)(rp + kb * 32 + 4);
        }
    }

#pragma unroll
    for (int mt = 0; mt < 4; ++mt) {
        // ---- pack current tile's A-frags (frees ld for prefetch) ----
        FragU af[4];
#pragma unroll
        for (int kb = 0; kb < 4; ++kb) {
            const float4 v0 = ld[kb * 2 + 0];
            const float4 v1 = ld[kb * 2 + 1];
            af[kb].u = make_uint4(rpack(v0.x, v0.y), rpack(v0.z, v0.w),
                                  rpack(v1.x, v1.y), rpack(v1.z, v1.w));
        }
        // ---- issue next tile's loads (fly under compute below) ----
        if (mt < 3) {
            const float* rp = x + (nodebase + (size_t)(mt + 1) * 16 + c) * D_ + q * 8;
#pragma unroll
            for (int kb = 0; kb < 4; ++kb) {
                ld[kb * 2 + 0] = *(const float4*)(rp + kb * 32);
                ld[kb * 2 + 1] = *(const float4*)(rp + kb * 32 + 4);
            }
        }

        // ---- layer 1: h[16 nodes x 32 j], 8 MFMA ----
        f32x4 acc0 = {b1v0, b1v0, b1v0, b1v0};
        f32x4 acc1 = {b1v1, b1v1, b1v1, b1v1};
#pragma unroll
        for (int kb = 0; kb < 4; ++kb) {
            const bf16x8 bh0 = *(const bf16x8*)&w1s[((kb * 2 + 0) * 4 + q) * 128 + c * 8];
            const bf16x8 bh1 = *(const bf16x8*)&w1s[((kb * 2 + 1) * 4 + q) * 128 + c * 8];
            acc0 = __builtin_amdgcn_mfma_f32_16x16x32_bf16(af[kb].v, bh0, acc0, 0, 0, 0);
            acc1 = __builtin_amdgcn_mfma_f32_16x16x32_bf16(af[kb].v, bh1, acc1, 0, 0, 0);
        }

        // ---- relu + store h (bf16 in u32 slots) to swizzled wave LDS ----
        // R8-validated addressing: (row*32 + col) ^ ((row&7)<<2), cols c, c+16
#pragma unroll
        for (int r = 0; r < 4; ++r) {
            const int row = q * 4 + r;
            const int xsw = (row & 7) << 2;
            hw[(row * 32 + c) ^ xsw] =
                (unsigned)(unsigned short)rbf16(fmaxf(acc0[r], 0.f));
            hw[(row * 32 + 16 + c) ^ xsw] =
                (unsigned)(unsigned short)rbf16(fmaxf(acc1[r], 0.f));
        }

        // ---- layer 2 A-frag: node=c, j=q*8+e (offsets INSIDE the XOR) ----
        const int hsw = (c & 7) << 2;
        const uint4 u0 = *(const uint4*)&hw[(c * 32 + q * 8) ^ hsw];
        const uint4 u1 = *(const uint4*)&hw[(c * 32 + q * 8 + 4) ^ hsw];
        FragU ha;
        ha.u.x = (u0.x & 0xffffu) | (u0.y << 16);
        ha.u.y = (u0.z & 0xffffu) | (u0.w << 16);
        ha.u.z = (u1.x & 0xffffu) | (u1.y << 16);
        ha.u.w = (u1.z & 0xffffu) | (u1.w << 16);

        f32x4 lacc = {b2v, b2v, b2v, b2v};
        lacc = __builtin_amdgcn_mfma_f32_16x16x32_bf16(ha.v, w2f.v, lacc, 0, 0, 0);

        // ---- softmax over K=16 (no max-subtract; |logit| small) ----
        float ex0 = __expf(lacc[0]);
        float ex1 = __expf(lacc[1]);
        float ex2 = __expf(lacc[2]);
        float ex3 = __expf(lacc[3]);
        float s0 = ex0, s1 = ex1, s2 = ex2, s3 = ex3;
#pragma unroll
        for (int s = 1; s < 16; s <<= 1) {
            s0 += __shfl_xor(s0, s, 16);
            s1 += __shfl_xor(s1, s, 16);
            s2 += __shfl_xor(s2, s, 16);
            s3 += __shfl_xor(s3, s, 16);
        }
        const size_t ob = (nodebase + (size_t)mt * 16 + q * 4) * K_ + c;
        assign_out[ob + 0 * K_] = ex0 / s0;
        assign_out[ob + 1 * K_] = ex1 / s1;
        assign_out[ob + 2 * K_] = ex2 / s2;
        assign_out[ob + 3 * K_] = ex3 / s3;
    }
}

// ---------------------------------------------------------------------------
// Kernel 2 (v4): coarse segment-sum + fused edge writer (unchanged, ~6 us).
// ---------------------------------------------------------------------------
#define FMA4(dst, v, sc)                                                      \
    dst.x = fmaf(v.x, sc, dst.x); dst.y = fmaf(v.y, sc, dst.y);               \
    dst.z = fmaf(v.z, sc, dst.z); dst.w = fmaf(v.w, sc, dst.w)

__global__ __launch_bounds__(1024, 4) void coarse_kernel(
    const float* __restrict__ x, const float* __restrict__ assign,
    const int* __restrict__ n_node, float* __restrict__ out)
{
    __shared__ float xs[2][32 * 128];
    __shared__ float as_[2][32 * 16];
    __shared__ int pref[G_];

    const int tid = threadIdx.x;
    const int g = blockIdx.x;

    if (tid < 256) {
        const int e = g * 256 + tid;
        out[OFF_SEND + e] = (float)(g * K_ + (tid >> 4));
        out[OFF_RECV + e] = (float)(g * K_ + (tid & 15));
        out[OFF_EDGE + e] = 1.0f;
    }

    if (tid < G_) pref[tid] = n_node[tid];
    __syncthreads();
    for (int st = 1; st < G_; st <<= 1) {
        int v = 0;
        if (tid < G_ && tid >= st) v = pref[tid - st];
        __syncthreads();
        if (tid < G_ && tid >= st) pref[tid] += v;
        __syncthreads();
    }
    const int start = (g == 0) ? 0 : min(pref[g - 1], N_);
    const int end   = (g == G_ - 1) ? N_ : min(pref[g], N_);

    const int dq = tid & 31;
    const int s  = tid >> 5;

    float4 acc[K_];
#pragma unroll
    for (int k = 0; k < K_; ++k) acc[k] = make_float4(0.f, 0.f, 0.f, 0.f);

    const int total = end - start;
    const int nfull = total >> 5;
    const int tail  = total & 31;

    float4 rx = make_float4(0.f, 0.f, 0.f, 0.f);
    float4 ra = make_float4(0.f, 0.f, 0.f, 0.f);
    if (nfull > 0) {
        rx = *(const float4*)(x + (size_t)start * D_ + tid * 4);
        if (tid < 128)
            ra = *(const float4*)(assign + (size_t)start * K_ + tid * 4);
    }

    int b = 0;
    for (int cc = 0; cc < nfull; ++cc) {
        *(float4*)(&xs[b][tid * 4]) = rx;
        if (tid < 128) *(float4*)(&as_[b][tid * 4]) = ra;
        __syncthreads();

        if (cc + 1 < nfull) {
            const size_t nb = (size_t)start + (size_t)(cc + 1) * 32;
            rx = *(const float4*)(x + nb * D_ + tid * 4);
            if (tid < 128)
                ra = *(const float4*)(assign + nb * K_ + tid * 4);
        }

        const float4 xv = *(const float4*)(&xs[b][s * D_ + dq * 4]);
        const float4* av = (const float4*)(&as_[b][s * K_]);
#pragma unroll
        for (int qq = 0; qq < 4; ++qq) {
            const float4 a = av[qq];
            FMA4(acc[4 * qq + 0], xv, a.x);
            FMA4(acc[4 * qq + 1], xv, a.y);
            FMA4(acc[4 * qq + 2], xv, a.z);
            FMA4(acc[4 * qq + 3], xv, a.w);
        }
        b ^= 1;
    }

    if (tail > 0 && s < tail) {
        const size_t n = (size_t)start + (size_t)nfull * 32 + s;
        const float4 xv = *(const float4*)(x + n * D_ + dq * 4);
        const float4* av = (const float4*)(assign + n * K_);
#pragma unroll
        for (int qq = 0; qq < 4; ++qq) {
            const float4 a = av[qq];
            FMA4(acc[4 * qq + 0], xv, a.x);
            FMA4(acc[4 * qq + 1], xv, a.y);
            FMA4(acc[4 * qq + 2], xv, a.z);
            FMA4(acc[4 * qq + 3], xv, a.w);
        }
    }

    __syncthreads();
    float* red = &xs[0][0];
#pragma unroll
    for (int k = 0; k < K_; ++k) {
        *(float4*)(&red[s * D_ + dq * 4]) = acc[k];
        __syncthreads();
        if (tid < D_) {
            float sum = 0.f;
#pragma unroll
            for (int ss = 0; ss < 32; ++ss) sum += red[ss * D_ + tid];
            out[OFF_COARSE + ((size_t)g * K_ + k) * D_ + tid] = sum;
        }
        __syncthreads();
    }
}

extern "C" void kernel_launch(void* const* d_in, const int* in_sizes, int n_in,
                              void* d_out, int out_size, void* d_ws, size_t ws_size,
                              hipStream_t stream)
{
    const float* x      = (const float*)d_in[0];
    const float* W1     = (const float*)d_in[1];
    const float* b1     = (const float*)d_in[2];
    const float* W2     = (const float*)d_in[3];
    const float* b2     = (const float*)d_in[4];
    const int*   n_node = (const int*)d_in[5];
    float* out = (float*)d_out;

    mlp_assign_mfma<<<N_ / 256, 256, 0, stream>>>(x, W1, b1, W2, b2, out + OFF_ASSIGN);
    coarse_kernel<<<G_, 1024, 0, stream>>>(x, out + OFF_ASSIGN, n_node, out);
}